// Round 8
// baseline (813.345 us; speedup 1.0000x reference)
//
#include <hip/hip_runtime.h>
#include <hip/hip_bf16.h>
#include <stdint.h>

typedef __bf16 bf16x8 __attribute__((ext_vector_type(8)));
typedef float  f32x4  __attribute__((ext_vector_type(4)));
typedef unsigned short ushort8v __attribute__((ext_vector_type(8)));

#define NSLOPE 0.01f

// problem dims
#define NB   32
#define CIN  128
#define HIN  130
#define WIN  130
#define KOUT 256
#define POUT 128
#define QOUT 128
#define HWIN (HIN*WIN)            // 16900
#define PQ   (POUT*QOUT)

// workspace: X' (NHWC bf16) then W' ([rsidx][k 256][ci 64] bf16)
#define XP_BYTES 138444800ull     // 32*130*130*128*2
#define WP_ELEMS (2*3*3*KOUT*64)  // 294912

// LDS (dynamic 132096 B): W dbuf 2x32768 @0 ; X slab 4 h-rows x 130 w x 128 B = 66560 @65536
#define WS_BYTES 32768
#define XS_BASE  65536
#define LDS_TOTAL 132096

__device__ __forceinline__ unsigned short f2bf(float f) {
    unsigned u = __builtin_bit_cast(unsigned, f);
    u += 0x7FFFu + ((u >> 16) & 1u);   // RNE
    return (unsigned short)(u >> 16);
}

__device__ __forceinline__ void g2lds16(const void* g, void* l) {
    __builtin_amdgcn_global_load_lds(
        (const __attribute__((address_space(1))) void*)g,
        (__attribute__((address_space(3))) void*)l,
        16, 0, 0);
}

// ---------------- pre-pass 1: X NCHW fp32 -> NHWC bf16 ----------------
__global__ __launch_bounds__(256) void k_conv_x(const float* __restrict__ X,
                                                unsigned short* __restrict__ Xp) {
    __shared__ unsigned short tile[130*132];   // [w][c], c padded 128->132
    const int b = blockIdx.x;                  // n*130 + h
    const int n = b / 130, h = b - n*130;
    const int tid = threadIdx.x;
    const size_t in_base = (size_t)n*(CIN*(size_t)HWIN) + (size_t)h*WIN;
    for (int fi = tid; fi < CIN*65; fi += 256) {
        int c = fi / 65, w2 = fi - c*65;
        float2 v = *(const float2*)(X + in_base + (size_t)c*HWIN + w2*2);
        tile[(w2*2  )*132 + c] = f2bf(v.x);
        tile[(w2*2+1)*132 + c] = f2bf(v.y);
    }
    __syncthreads();
    unsigned short* outp = Xp + (size_t)b * (WIN*CIN);
    for (int oi = tid; oi < (WIN*CIN)/8; oi += 256) {
        int e = oi*8; int w = e >> 7; int c8 = e & 127;
        const unsigned short* t = &tile[w*132 + c8];
        ushort8v v;
        #pragma unroll
        for (int j = 0; j < 8; ++j) v[j] = t[j];
        *(ushort8v*)(outp + e) = v;
    }
}

// ---------------- pre-pass 2: W OIHW fp32 -> W' [rsidx][k][ci] bf16 ----------------
__global__ __launch_bounds__(256) void k_conv_w(const float* __restrict__ W,
                                                unsigned short* __restrict__ Wp) {
    int e = blockIdx.x*256 + threadIdx.x;
    if (e >= WP_ELEMS) return;
    int ci = e & 63;
    int k  = (e >> 6) & 255;
    int rsIdx = e >> 14;                       // 0..17 = cc*9 + r*3 + s
    int cc = rsIdx / 9; int rem = rsIdx - cc*9; int r = rem / 3, s = rem - r*3;
    int c = cc*64 + ci;
    Wp[e] = f2bf(W[(size_t)k*1152 + (size_t)c*9 + r*3 + s]);
}

// ---------------- staging (linear LDS dest, inverse-swizzled global src) ----------------
// swizzle: phys = logical ^ ((row&7)<<4), rows are 128 B
__device__ __forceinline__ void stage_w(const unsigned short* __restrict__ Wp,
                                        unsigned char* lds, int rsidx, int tid) {
    const unsigned short* wbase = Wp + (size_t)rsidx * (KOUT*64);
    #pragma unroll
    for (int it = 0; it < 8; ++it) {
        const int t    = it*256 + tid;
        const int phys = t << 4;
        const int row  = phys >> 7;                      // kout 0..255
        const int cib  = (phys & 127) ^ ((row & 7) << 4);
        g2lds16(wbase + (size_t)row*64 + (cib >> 1), lds + phys);
    }
}

// stage 4 h-rows (p2..p2+3), all 130 w, 64 ci of channel-half cc: 4160 granules
__device__ __forceinline__ void stage_x4(const unsigned short* __restrict__ Xp,
                                         unsigned char* lds, int n, int p2, int cc, int tid) {
    #pragma unroll
    for (int it = 0; it < 17; ++it) {
        const int t = it*256 + tid;
        if (t < 4160) {
            const int phys = t << 4;
            const int g    = phys >> 7;                  // rloc*130 + w, 0..519
            const int rloc = g / 130;
            const int w    = g - 130*rloc;
            const int cib  = (phys & 127) ^ ((g & 7) << 4);
            const unsigned short* src =
                Xp + ((size_t)((n*HIN + p2 + rloc)*WIN + w))*CIN + cc*64 + (cib >> 1);
            g2lds16(src, lds + phys);
        }
    }
}

// ---------------- main conv: 256 kout x 256 pq tile, 4 waves of 128x128 ----------------
__global__ __launch_bounds__(256, 1) void k_conv_main(
    const unsigned short* __restrict__ Xp,
    const unsigned short* __restrict__ Wp,
    const float* __restrict__ bias,
    float* __restrict__ out)
{
    extern __shared__ __align__(16) unsigned char smem[];

    const int tid  = threadIdx.x;
    const int lane = tid & 63;
    const int wid  = tid >> 6;
    const int wmw  = wid >> 1;         // kout 128-half
    const int wnw  = wid & 1;          // p-row within the pair
    const int l15  = lane & 15;
    const int kg16 = (lane >> 4) << 4;

    // bijective XCD swizzle (2048 = 8 x 256)
    const int L  = ((blockIdx.x & 7) << 8) | (blockIdx.x >> 3);
    const int n  = L >> 6;
    const int p2 = (L & 63) << 1;

    unsigned char* xs = smem + XS_BASE;

    // A base: row = wmw*128 + mf*16 + l15 -> (row&7) = l15&7 invariant; mf -> +2048 B
    const int rowA0 = wmw*128 + l15;
    const int swA   = (l15 & 7) << 4;

    f32x4 acc[8][8];
    #pragma unroll
    for (int i = 0; i < 8; ++i)
        #pragma unroll
        for (int j = 0; j < 8; ++j)
            acc[i][j] = (f32x4){0.f, 0.f, 0.f, 0.f};

    // prologue
    stage_w(Wp, smem, 0, tid);
    stage_x4(Xp, xs, n, p2, 0, tid);
    asm volatile("s_waitcnt vmcnt(0)" ::: "memory");
    __syncthreads();

    #pragma unroll 1
    for (int t = 0; t < 18; ++t) {
        const int cc  = t / 9;
        const int rem = t - cc*9;
        const int rr  = rem / 3;
        const int s   = rem - rr*3;
        unsigned char* wsR = smem + (t & 1)*WS_BYTES;
        unsigned char* wsW = smem + ((t + 1) & 1)*WS_BYTES;

        if (t < 17) stage_w(Wp, wsW, t + 1, tid);

        // B base: g = (wnw+rr)*130 + nf*16 + l15 + s -> (g&7) invariant under nf
        const int g0  = (wnw + rr)*130 + l15 + s;
        const int swB = (g0 & 7) << 4;

        #pragma unroll
        for (int kq = 0; kq < 2; ++kq) {
            const int cib0 = kq*64 + kg16;
            const int aB = rowA0*128 + (cib0 ^ swA);
            const int bB = g0*128   + (cib0 ^ swB);
            bf16x8 A[8], B[8];
            #pragma unroll
            for (int mf = 0; mf < 8; ++mf)
                A[mf] = *(const bf16x8*)(wsR + aB + mf*2048);
            #pragma unroll
            for (int nf = 0; nf < 8; ++nf)
                B[nf] = *(const bf16x8*)(xs + bB + nf*2048);
            #pragma unroll
            for (int mf = 0; mf < 8; ++mf)
                #pragma unroll
                for (int nf = 0; nf < 8; ++nf)
                    acc[mf][nf] = __builtin_amdgcn_mfma_f32_16x16x32_bf16(
                        A[mf], B[nf], acc[mf][nf], 0, 0, 0);
        }

        asm volatile("s_waitcnt vmcnt(0)" ::: "memory");  // W(t+1) landed (issued ~2500 cyc ago)
        __syncthreads();

        if (t == 8) {   // cc boundary: restage X slab (one-time drain)
            stage_x4(Xp, xs, n, p2, 1, tid);
            asm volatile("s_waitcnt vmcnt(0)" ::: "memory");
            __syncthreads();
        }
    }

    // epilogue: D col(q) = lane&15, row(kout) = kg*4 + j -> coalesced 64-B segments
    const int kg = lane >> 4;
    #pragma unroll
    for (int mf = 0; mf < 8; ++mf) {
        const int kb = wmw*128 + mf*16 + kg*4;
        const float4 bv = *(const float4*)(bias + kb);
        const float bj[4] = {bv.x, bv.y, bv.z, bv.w};
        #pragma unroll
        for (int nf = 0; nf < 8; ++nf) {
            const int q = nf*16 + l15;
            const size_t base = (((size_t)n*KOUT + kb)*POUT + (p2 + wnw))*QOUT + q;
            #pragma unroll
            for (int j = 0; j < 4; ++j) {
                float y = (acc[mf][nf][j] + bj[j]) * 0.5f;
                out[base + (size_t)j*PQ] = (y >= 0.f) ? y : y*NSLOPE;
            }
        }
    }
}

extern "C" void kernel_launch(void* const* d_in, const int* in_sizes, int n_in,
                              void* d_out, int out_size, void* d_ws, size_t ws_size,
                              hipStream_t stream) {
    const float* X = (const float*)d_in[0];
    const float* W = (const float*)d_in[1];
    const float* B = (const float*)d_in[2];
    float* out = (float*)d_out;
    unsigned short* Xp = (unsigned short*)d_ws;
    unsigned short* Wp = (unsigned short*)((char*)d_ws + XP_BYTES);

    (void)hipFuncSetAttribute((const void*)k_conv_main,
                              hipFuncAttributeMaxDynamicSharedMemorySize, LDS_TOTAL);

    k_conv_x   <<<NB*HIN, 256, 0, stream>>>(X, Xp);
    k_conv_w   <<<(WP_ELEMS + 255)/256, 256, 0, stream>>>(W, Wp);
    k_conv_main<<<2048, 256, LDS_TOTAL, stream>>>(Xp, Wp, B, out);
}

// Round 9
// 395.079 us; speedup vs baseline: 2.0587x; 2.0587x over previous
//
#include <hip/hip_runtime.h>
#include <hip/hip_bf16.h>
#include <stdint.h>

typedef __bf16 bf16x8 __attribute__((ext_vector_type(8)));
typedef float  f32x4  __attribute__((ext_vector_type(4)));

#define NSLOPE 0.01f

// problem dims
#define NB   32
#define CIN  128
#define HIN  130
#define WIN  130
#define KOUT 256
#define POUT 128
#define QOUT 128
#define HWIN (HIN*WIN)            // 16900
#define PQ   (POUT*QOUT)

// workspace: X' (NHWC bf16) then W' ([rsidx][k 256][ci 64] bf16)
#define XP_BYTES 138444800ull     // 32*130*130*128*2
#define WP_ELEMS (2*3*3*KOUT*64)  // 294912

// LDS (conv): W tile [128 kout][64 ci] = 16384 B @0 ; X tile [130 w][64 ci] = 16640 B @16384
// 33024 B total -> 4 blocks/CU
#define XT_OFF    16384
#define LDS_TOTAL (16384 + 16640)

__device__ __forceinline__ unsigned short f2bf(float f) {
    unsigned u = __builtin_bit_cast(unsigned, f);
    u += 0x7FFFu + ((u >> 16) & 1u);   // RNE
    return (unsigned short)(u >> 16);
}

__device__ __forceinline__ void g2lds16(const void* g, void* l) {
    __builtin_amdgcn_global_load_lds(
        (const __attribute__((address_space(1))) void*)g,
        (__attribute__((address_space(3))) void*)l,
        16, 0, 0);
}

// ---------------- pre-pass 1: X NCHW fp32 -> NHWC bf16 (dword-packed transpose) ----------------
// LDS tile = dwords [c2 64][w 130 pad 131]: writes lane-consecutive along w (conflict-free),
// reads 4x strided ds_read_b32 (~2-way), output 16-B coalesced.
__global__ __launch_bounds__(256) void k_conv_x(const float* __restrict__ X,
                                                unsigned short* __restrict__ Xp) {
    __shared__ unsigned int tile[64*131];      // 33536 B
    const int b = blockIdx.x;                  // n*130 + h
    const int n = b / 130, h = b - n*130;
    const int tid = threadIdx.x;
    const size_t in0 = (size_t)n*(CIN*(size_t)HWIN) + (size_t)h*WIN;
    for (int fi = tid; fi < 64*130; fi += 256) {
        const int c2 = fi / 130, w = fi - c2*130;
        const float lo = X[in0 + (size_t)(2*c2  )*HWIN + w];
        const float hi = X[in0 + (size_t)(2*c2+1)*HWIN + w];
        tile[c2*131 + w] = (unsigned)f2bf(lo) | ((unsigned)f2bf(hi) << 16);
    }
    __syncthreads();
    unsigned int* outp = (unsigned int*)(Xp + (size_t)b*(WIN*CIN));
    for (int oi = tid; oi < 2080; oi += 256) {           // 130 w x 16 chunks
        const int w = oi >> 4, j4 = (oi & 15) << 2;      // c2 = j4..j4+3
        uint4 v;
        v.x = tile[(j4+0)*131 + w];
        v.y = tile[(j4+1)*131 + w];
        v.z = tile[(j4+2)*131 + w];
        v.w = tile[(j4+3)*131 + w];
        *(uint4*)(outp + w*64 + j4) = v;                 // dword idx = w*64 + c2
    }
}

// ---------------- pre-pass 2: W OIHW fp32 -> W' [rsidx][k][ci] bf16 ----------------
__global__ __launch_bounds__(256) void k_conv_w(const float* __restrict__ W,
                                                unsigned short* __restrict__ Wp) {
    int e = blockIdx.x*256 + threadIdx.x;
    if (e >= WP_ELEMS) return;
    int ci = e & 63;
    int k  = (e >> 6) & 255;
    int rsIdx = e >> 14;                       // 0..17 = cc*9 + r*3 + s
    int cc = rsIdx / 9; int rem = rsIdx - cc*9; int r = rem / 3, s = rem - r*3;
    int c = cc*64 + ci;
    Wp[e] = f2bf(W[(size_t)k*1152 + (size_t)c*9 + r*3 + s]);
}

// ---------------- main conv (R6 structure): 128 kout x 128 q, 2 waves of 64x128, 4 blocks/CU ----------------
// swizzle: phys = logical ^ ((row&7)<<4), rows are 128 B
__global__ __launch_bounds__(128, 2) void k_conv_main(
    const unsigned short* __restrict__ Xp,
    const unsigned short* __restrict__ Wp,
    const float* __restrict__ bias,
    float* __restrict__ out)
{
    __shared__ __align__(16) unsigned char smem[LDS_TOTAL];

    const int tid  = threadIdx.x;
    const int lane = tid & 63;
    const int wm   = tid >> 6;        // 0..1: kout 64-block within the kh-half
    const int l15  = lane & 15;
    const int kg16 = (lane >> 4) << 4;

    // grid 8192 = 8 XCD-chunks x 1024; L = n*256 + p*2 + kh (kh pairs adjacent, same XCD)
    const int L  = ((blockIdx.x & 7) << 10) | (blockIdx.x >> 3);
    const int kh = L & 1;
    const int np = L >> 1;
    const int p  = np & 127;
    const int n  = np >> 7;

    f32x4 acc[4][8];
    #pragma unroll
    for (int i = 0; i < 4; ++i)
        #pragma unroll
        for (int j = 0; j < 8; ++j)
            acc[i][j] = (f32x4){0.f, 0.f, 0.f, 0.f};

    #pragma unroll 1
    for (int t = 0; t < 18; ++t) {
        const int cc = t / 9;
        const int rem = t - cc*9;
        const int r  = rem / 3;
        const int s  = rem - r*3;

        __syncthreads();   // all reads of both tiles from previous step complete

        // stage W(cc,r,s): 1024 granules over 128 threads
        {
            const unsigned short* wbase = Wp + (size_t)t*(KOUT*64) + (size_t)(kh*128)*64;
            #pragma unroll
            for (int it = 0; it < 8; ++it) {
                const int g    = it*128 + tid;
                const int phys = g << 4;
                const int row  = phys >> 7;                      // kout-local 0..127
                const int cib  = (phys & 127) ^ ((row & 7) << 4);
                g2lds16(wbase + (size_t)row*64 + (cib >> 1), smem + phys);
            }
        }
        // stage X(cc, p+r): 1040 granules (only when r advances)
        if (s == 0) {
            const unsigned short* xbase =
                Xp + ((size_t)((n*HIN + (p + r))*WIN))*CIN + cc*64;
            #pragma unroll
            for (int it = 0; it < 9; ++it) {
                const int g = it*128 + tid;
                if (g < 1040) {
                    const int phys = g << 4;
                    const int w    = phys >> 7;                  // 0..129
                    const int cib  = (phys & 127) ^ ((w & 7) << 4);
                    g2lds16(xbase + (size_t)w*CIN + (cib >> 1), smem + XT_OFF + phys);
                }
            }
        }

        __syncthreads();   // drains vmcnt: tiles ready

        #pragma unroll
        for (int kq = 0; kq < 2; ++kq) {
            const int cib0 = kq*64 + kg16;
            bf16x8 A[4], B[8];
            #pragma unroll
            for (int mf = 0; mf < 4; ++mf) {
                const int row = wm*64 + mf*16 + l15;
                A[mf] = *(const bf16x8*)(smem + row*128 + (cib0 ^ ((row & 7) << 4)));
            }
            #pragma unroll
            for (int nf = 0; nf < 8; ++nf) {
                const int g = nf*16 + l15 + s;                   // w = q + s
                B[nf] = *(const bf16x8*)(smem + XT_OFF + g*128 + (cib0 ^ ((g & 7) << 4)));
            }
            // T5: blocks on a CU are phase-staggered (4 independent blocks) -> setprio regime
            __builtin_amdgcn_s_setprio(1);
            #pragma unroll
            for (int mf = 0; mf < 4; ++mf)
                #pragma unroll
                for (int nf = 0; nf < 8; ++nf)
                    acc[mf][nf] = __builtin_amdgcn_mfma_f32_16x16x32_bf16(
                        A[mf], B[nf], acc[mf][nf], 0, 0, 0);
            __builtin_amdgcn_s_setprio(0);
        }
    }

    // epilogue: D col(q) = lane&15, row(kout) = kg*4 + j -> coalesced 64-B segments
    const int kg = lane >> 4;
    #pragma unroll
    for (int mf = 0; mf < 4; ++mf) {
        const int kb = kh*128 + wm*64 + mf*16 + kg*4;
        const float4 bv = *(const float4*)(bias + kb);
        const float bj[4] = {bv.x, bv.y, bv.z, bv.w};
        #pragma unroll
        for (int nf = 0; nf < 8; ++nf) {
            const int q = nf*16 + l15;
            const size_t base = (((size_t)n*KOUT + kb)*POUT + p)*QOUT + q;
            #pragma unroll
            for (int j = 0; j < 4; ++j) {
                float y = (acc[mf][nf][j] + bj[j]) * 0.5f;
                out[base + (size_t)j*PQ] = (y >= 0.f) ? y : y*NSLOPE;
            }
        }
    }
}

extern "C" void kernel_launch(void* const* d_in, const int* in_sizes, int n_in,
                              void* d_out, int out_size, void* d_ws, size_t ws_size,
                              hipStream_t stream) {
    const float* X = (const float*)d_in[0];
    const float* W = (const float*)d_in[1];
    const float* B = (const float*)d_in[2];
    float* out = (float*)d_out;
    unsigned short* Xp = (unsigned short*)d_ws;
    unsigned short* Wp = (unsigned short*)((char*)d_ws + XP_BYTES);

    k_conv_x   <<<NB*HIN, 256, 0, stream>>>(X, Xp);
    k_conv_w   <<<(WP_ELEMS + 255)/256, 256, 0, stream>>>(W, Wp);
    k_conv_main<<<8192, 128, 0, stream>>>(Xp, Wp, B, out);
}

// Round 10
// 390.724 us; speedup vs baseline: 2.0816x; 1.0111x over previous
//
#include <hip/hip_runtime.h>
#include <hip/hip_bf16.h>
#include <stdint.h>

typedef __bf16 bf16x8 __attribute__((ext_vector_type(8)));
typedef float  f32x4  __attribute__((ext_vector_type(4)));

#define NSLOPE 0.01f

// problem dims
#define NB   32
#define CIN  128
#define HIN  130
#define WIN  130
#define KOUT 256
#define POUT 128
#define QOUT 128
#define HWIN (HIN*WIN)            // 16900
#define PQ   (POUT*QOUT)

// workspace: X' (NHWC bf16) then W' ([rsidx][k 256][ci 64] bf16)
#define XP_BYTES 138444800ull     // 32*130*130*128*2
#define WP_ELEMS (2*3*3*KOUT*64)  // 294912

// LDS (conv): W tile [128 kout][64 ci] = 16384 B @0 ; X tile [130 w][64 ci] = 16640 B @16384
// 33024 B total -> 4 blocks/CU
#define XT_OFF    16384
#define LDS_TOTAL (16384 + 16640)

__device__ __forceinline__ unsigned short f2bf(float f) {
    unsigned u = __builtin_bit_cast(unsigned, f);
    u += 0x7FFFu + ((u >> 16) & 1u);   // RNE
    return (unsigned short)(u >> 16);
}

__device__ __forceinline__ void g2lds16(const void* g, void* l) {
    __builtin_amdgcn_global_load_lds(
        (const __attribute__((address_space(1))) void*)g,
        (__attribute__((address_space(3))) void*)l,
        16, 0, 0);
}

// ---------------- pre-pass: X NCHW fp32 -> NHWC bf16 (blocks < 4160)
//                  + W OIHW fp32 -> W' [rsidx][k][ci] (blocks >= 4160) ----------------
__global__ __launch_bounds__(256) void k_conv_xw(const float* __restrict__ X,
                                                 const float* __restrict__ W,
                                                 unsigned short* __restrict__ Xp,
                                                 unsigned short* __restrict__ Wp) {
    __shared__ unsigned int tile[64*131];      // 33536 B
    const int tid = threadIdx.x;

    if (blockIdx.x >= NB*HIN) {                // W-convert tail: 1152 blocks
        int e = (blockIdx.x - NB*HIN)*256 + tid;
        if (e < WP_ELEMS) {
            int ci = e & 63;
            int k  = (e >> 6) & 255;
            int rsIdx = e >> 14;               // 0..17 = cc*9 + r*3 + s
            int cc = rsIdx / 9; int rem = rsIdx - cc*9; int r = rem / 3, s = rem - r*3;
            int c = cc*64 + ci;
            Wp[e] = f2bf(W[(size_t)k*1152 + (size_t)c*9 + r*3 + s]);
        }
        return;
    }

    const int b = blockIdx.x;                  // n*130 + h
    const int n = b / 130, h = b - n*130;
    const size_t in0 = (size_t)n*(CIN*(size_t)HWIN) + (size_t)h*WIN;
    for (int fi = tid; fi < 64*130; fi += 256) {
        const int c2 = fi / 130, w = fi - c2*130;
        const float lo = X[in0 + (size_t)(2*c2  )*HWIN + w];
        const float hi = X[in0 + (size_t)(2*c2+1)*HWIN + w];
        tile[c2*131 + w] = (unsigned)f2bf(lo) | ((unsigned)f2bf(hi) << 16);
    }
    __syncthreads();
    unsigned int* outp = (unsigned int*)(Xp + (size_t)b*(WIN*CIN));
    for (int oi = tid; oi < 2080; oi += 256) {           // 130 w x 16 chunks
        const int w = oi >> 4, j4 = (oi & 15) << 2;      // c2 = j4..j4+3
        uint4 v;
        v.x = tile[(j4+0)*131 + w];
        v.y = tile[(j4+1)*131 + w];
        v.z = tile[(j4+2)*131 + w];
        v.w = tile[(j4+3)*131 + w];
        *(uint4*)(outp + w*64 + j4) = v;                 // dword idx = w*64 + c2
    }
}

// ---------------- main conv body (R9 structure), templated on base priority ----------------
// swizzle: phys = logical ^ ((row&7)<<4), rows are 128 B
template<int PRIO>
__device__ __forceinline__ void conv_body(
    const unsigned short* __restrict__ Xp,
    const unsigned short* __restrict__ Wp,
    const float* __restrict__ bias,
    float* __restrict__ out,
    unsigned char* smem, int tid, int L)
{
    const int lane = tid & 63;
    const int wm   = tid >> 6;        // 0..1: kout 64-block within the kh-half
    const int l15  = lane & 15;
    const int kg16 = (lane >> 4) << 4;

    const int kh = L & 1;
    const int np = L >> 1;
    const int p  = np & 127;
    const int n  = np >> 7;

    f32x4 acc[4][8];
    #pragma unroll
    for (int i = 0; i < 4; ++i)
        #pragma unroll
        for (int j = 0; j < 8; ++j)
            acc[i][j] = (f32x4){0.f, 0.f, 0.f, 0.f};

    #pragma unroll 1
    for (int t = 0; t < 18; ++t) {
        const int cc = t / 9;
        const int rem = t - cc*9;
        const int r  = rem / 3;
        const int s  = rem - r*3;

        __syncthreads();   // all reads of both tiles from previous step complete

        {   // stage W(cc,r,s): 1024 granules over 128 threads
            const unsigned short* wbase = Wp + (size_t)t*(KOUT*64) + (size_t)(kh*128)*64;
            #pragma unroll
            for (int it = 0; it < 8; ++it) {
                const int g    = it*128 + tid;
                const int phys = g << 4;
                const int row  = phys >> 7;                      // kout-local 0..127
                const int cib  = (phys & 127) ^ ((row & 7) << 4);
                g2lds16(wbase + (size_t)row*64 + (cib >> 1), smem + phys);
            }
        }
        if (s == 0) {   // stage X(cc, p+r): 1040 granules
            const unsigned short* xbase =
                Xp + ((size_t)((n*HIN + (p + r))*WIN))*CIN + cc*64;
            #pragma unroll
            for (int it = 0; it < 9; ++it) {
                const int g = it*128 + tid;
                if (g < 1040) {
                    const int phys = g << 4;
                    const int w    = phys >> 7;                  // 0..129
                    const int cib  = (phys & 127) ^ ((w & 7) << 4);
                    g2lds16(xbase + (size_t)w*CIN + (cib >> 1), smem + XT_OFF + phys);
                }
            }
        }

        __syncthreads();   // drains vmcnt: tiles ready

        #pragma unroll
        for (int kq = 0; kq < 2; ++kq) {
            const int cib0 = kq*64 + kg16;
            bf16x8 A[4], B[8];
            #pragma unroll
            for (int mf = 0; mf < 4; ++mf) {
                const int row = wm*64 + mf*16 + l15;
                A[mf] = *(const bf16x8*)(smem + row*128 + (cib0 ^ ((row & 7) << 4)));
            }
            #pragma unroll
            for (int nf = 0; nf < 8; ++nf) {
                const int g = nf*16 + l15 + s;                   // w = q + s
                B[nf] = *(const bf16x8*)(smem + XT_OFF + g*128 + (cib0 ^ ((g & 7) << 4)));
            }
            __builtin_amdgcn_s_setprio(PRIO + 1);
            #pragma unroll
            for (int mf = 0; mf < 4; ++mf)
                #pragma unroll
                for (int nf = 0; nf < 8; ++nf)
                    acc[mf][nf] = __builtin_amdgcn_mfma_f32_16x16x32_bf16(
                        A[mf], B[nf], acc[mf][nf], 0, 0, 0);
            __builtin_amdgcn_s_setprio(PRIO);
        }
    }

    // epilogue: D col(q) = lane&15, row(kout) = kg*4 + j -> coalesced 64-B segments
    const int kg = lane >> 4;
    #pragma unroll
    for (int mf = 0; mf < 4; ++mf) {
        const int kb = kh*128 + wm*64 + mf*16 + kg*4;
        const float4 bv = *(const float4*)(bias + kb);
        const float bj[4] = {bv.x, bv.y, bv.z, bv.w};
        #pragma unroll
        for (int nf = 0; nf < 8; ++nf) {
            const int q = nf*16 + l15;
            const size_t base = (((size_t)n*KOUT + kb)*POUT + p)*QOUT + q;
            #pragma unroll
            for (int j = 0; j < 4; ++j) {
                float y = (acc[mf][nf][j] + bj[j]) * 0.5f;
                out[base + (size_t)j*PQ] = (y >= 0.f) ? y : y*NSLOPE;
            }
        }
    }
}

// 128 kout x 128 q, 2 waves of 64x128, 4 blocks/CU; block-parity base priority
__global__ __launch_bounds__(128, 2) void k_conv_main(
    const unsigned short* __restrict__ Xp,
    const unsigned short* __restrict__ Wp,
    const float* __restrict__ bias,
    float* __restrict__ out)
{
    __shared__ __align__(16) unsigned char smem[LDS_TOTAL];

    // grid 8192 = 8 XCD-chunks x 1024; L = n*256 + p*2 + kh (kh pairs adjacent, same XCD)
    const int L = ((blockIdx.x & 7) << 10) | (blockIdx.x >> 3);

    // parity by ORIGINAL blockIdx: resident blocks on a CU are dispatch-consecutive,
    // so base priority alternates across co-resident blocks -> forced phase asymmetry
    if (blockIdx.x & 1) {
        __builtin_amdgcn_s_setprio(1);
        conv_body<1>(Xp, Wp, bias, out, smem, threadIdx.x, L);
    } else {
        conv_body<0>(Xp, Wp, bias, out, smem, threadIdx.x, L);
    }
}

extern "C" void kernel_launch(void* const* d_in, const int* in_sizes, int n_in,
                              void* d_out, int out_size, void* d_ws, size_t ws_size,
                              hipStream_t stream) {
    const float* X = (const float*)d_in[0];
    const float* W = (const float*)d_in[1];
    const float* B = (const float*)d_in[2];
    float* out = (float*)d_out;
    unsigned short* Xp = (unsigned short*)d_ws;
    unsigned short* Wp = (unsigned short*)((char*)d_ws + XP_BYTES);

    k_conv_xw  <<<NB*HIN + (WP_ELEMS + 255)/256, 256, 0, stream>>>(X, W, Xp, Wp);
    k_conv_main<<<8192, 128, 0, stream>>>(Xp, Wp, B, out);
}